// Round 3
// baseline (403.486 us; speedup 1.0000x reference)
//
#include <hip/hip_runtime.h>
#include <cmath>

#define EPSV 1e-5f

typedef short bf16x8 __attribute__((ext_vector_type(8)));
typedef float f32x4 __attribute__((ext_vector_type(4)));

__device__ __forceinline__ unsigned short f2bf(float f) {
  unsigned u = __float_as_uint(f);
  unsigned r = ((u >> 16) & 1u) + 0x7FFFu;   // RTNE
  return (unsigned short)((u + r) >> 16);
}

__device__ __forceinline__ void async16(const void* g, void* l) {
  __builtin_amdgcn_global_load_lds(
      (const __attribute__((address_space(1))) unsigned int*)g,
      (__attribute__((address_space(3))) unsigned int*)l, 16, 0, 0);
}

// ---- prep: weights fp32 -> bf16. w0 re-laid phase-contiguous: k = ph*196 + pair,
// K padded 588 -> 640 (zeros), so L0 runs 10 K64-intervals.
__global__ void prep_conv(const float* __restrict__ w0, const float* __restrict__ w1,
                          const float* __restrict__ w2, unsigned short* __restrict__ w0b,
                          unsigned short* __restrict__ w1b, unsigned short* __restrict__ w2b) {
  int idx = blockIdx.x * 256 + threadIdx.x;
  if (idx < 512 * 640) {
    int o = idx / 640, c = idx - o * 640;
    float v = 0.f;
    if (c < 588) { int ph = c / 196, q = c - ph * 196; v = w0[o * 588 + q * 3 + ph]; }
    w0b[idx] = f2bf(v);
    return;
  }
  idx -= 512 * 640;
  if (idx < 384 * 512) { w1b[idx] = f2bf(w1[idx]); return; }
  idx -= 384 * 512;
  if (idx < 256 * 384) { w2b[idx] = f2bf(w2[idx]); }
}

// ---- prep: softmax(weight_mask) -> wm[16][144] ----
__global__ void prep_wm(const float* __restrict__ wmask, float* __restrict__ wm) {
  int g = threadIdx.x >> 6, lane = threadIdx.x & 63;
  const float* row = wmask + g * 144;
  float v0 = row[lane], v1 = row[lane + 64];
  float v2 = (lane < 16) ? row[lane + 128] : -1e30f;
  float m = fmaxf(fmaxf(v0, v1), v2);
  for (int off = 32; off; off >>= 1) m = fmaxf(m, __shfl_xor(m, off));
  float e0 = expf(v0 - m), e1 = expf(v1 - m), e2 = (lane < 16) ? expf(v2 - m) : 0.f;
  float s = e0 + e1 + e2;
  for (int off = 32; off; off >>= 1) s += __shfl_xor(s, off);
  float inv = 1.f / s;
  wm[g * 144 + lane] = e0 * inv;
  wm[g * 144 + lane + 64] = e1 * inv;
  if (lane < 16) wm[g * 144 + lane + 128] = e2 * inv;
}

// ---------------- fused main ------------------------------------------------------
// K=64 per barrier interval. LDS overlay plan (bytes, 160 KiB):
//  L0 : B0 dbuf 2x64K [0,131072) | featbuf 2x8K [131072,147456) | xc [147456,154624)
//  L0 epi: h0 [0,65536) (overlays dead B0 buf0) ; prefetch B1 tile0 -> [65536,..)
//  L1 : B1 dbuf 2x48K [65536,163840) | h0 [0,65536)
//  L1 epi: h1 [0,49152) (overlays dead h0) ; prefetch B2 tile0
//  L2 : B2 dbuf 2x32K [65536,131072) | h1 [0,49152)
#define LDS_B0 0u
#define LDS_FB 131072u
#define LDS_XC 147456u
#define LDS_B1 65536u
#define LDS_B2 65536u

__launch_bounds__(512, 2)
__global__ void fused_main(const float* __restrict__ x, const float* __restrict__ b0,
                           const float* __restrict__ b1, const float* __restrict__ b2,
                           const unsigned short* __restrict__ w0b,
                           const unsigned short* __restrict__ w1b,
                           const unsigned short* __restrict__ w2b,
                           const float* __restrict__ wm, float* __restrict__ out) {
  __shared__ __align__(16) char lds[163840];
  const int tid = threadIdx.x;
  const int wv = tid >> 6, lane = tid & 63;
  const int quad = lane >> 4, l15 = lane & 15;
  const int r0 = blockIdx.x * 64;

  // ---- per-row xi/xj cache (14 each, fp32), with x[:,167]=0 override ----
  {
    int row = tid >> 3, idx = tid & 7;
    int r = r0 + row;
    int b = r / 144, p = r - b * 144;
    int h = p / 12, w = p - h * 12;
    const float* xb = x + b * 168;
    float* xi = (float*)(lds + LDS_XC) + row * 14;
    float* xj = (float*)(lds + LDS_XC + 3584) + row * 14;
    for (int ii = idx; ii < 14; ii += 8) {
      int i = ii * 12 + h;
      xi[ii] = (i == 167) ? 0.f : xb[i];
      int j = ii * 12 + w;
      xj[ii] = (j == 167) ? 0.f : xb[j];
    }
  }
  __syncthreads();

  // stage one K=64 B tile (N rows x 128B, 16B-chunk rotate-swizzle mod 8)
  auto stageB = [&](const unsigned short* wsrc, int rowstride, unsigned ldsbase, int k64, int ipw) {
    for (int i = 0; i < ipw; i++) {
      int blkid = wv * ipw + i;
      int nn = blkid * 8 + (lane >> 3);
      int cc = lane & 7;
      int q = (cc - nn) & 7;                       // inverse of read swizzle
      const char* g = (const char*)wsrc + nn * rowstride + k64 * 128 + q * 16;
      async16(g, lds + ldsbase + blkid * 1024u + lane * 16u);
    }
  };

  // generate one K=64 feat tile (64 rows x 128B, same rotate-swizzle mod 8)
  auto genF = [&](int t, unsigned fb) {
    int row = tid >> 3, c = tid & 7;
    const float* xi = (const float*)(lds + LDS_XC) + row * 14;
    const float* xj = (const float*)(lds + LDS_XC + 3584) + row * 14;
    int k0 = t * 64 + c * 8;
    unsigned short vs[8];
#pragma unroll
    for (int e = 0; e < 8; e++) {
      int k = k0 + e;
      float f = 0.f;
      if (k < 588) {
        int ph = (k >= 392) ? 2 : ((k >= 196) ? 1 : 0);
        int p0 = k - ph * 196;
        int i1 = p0 / 14, j1 = p0 - i1 * 14;
        float a = xi[i1], c2 = xj[j1];
        if (ph == 0) f = c2 - a;
        else {
          float rcp = __builtin_amdgcn_rcpf(a + c2 + EPSV);
          f = (ph == 1) ? (c2 - a) * rcp : c2 * rcp;
        }
      }
      vs[e] = f2bf(f);
    }
    *(bf16x8*)(lds + fb + row * 128u + ((c + row) & 7) * 16u) = *(const bf16x8*)vs;
  };

  // =================== Layer 0 : feat(640) -> 512 ===================
  {
    stageB(w0b, 1280, LDS_B0, 0, 8);
    genF(0, LDS_FB);
    __syncthreads();

    f32x4 acc[4][4];
#pragma unroll
    for (int a = 0; a < 4; a++)
#pragma unroll
      for (int c = 0; c < 4; c++) acc[a][c] = f32x4{0.f, 0.f, 0.f, 0.f};

    for (int p = 0; p < 10; p++) {
      unsigned bb = LDS_B0 + (p & 1) * 65536u;
      unsigned fb = LDS_FB + (p & 1) * 8192u;
      bf16x8 af[2][4], bfr[2][4];
#pragma unroll
      for (int s = 0; s < 2; s++) {
#pragma unroll
        for (int rt = 0; rt < 4; rt++) {
          int m = rt * 16 + l15;
          af[s][rt] = *(const bf16x8*)(lds + fb + m * 128u + (((s * 4 + quad) + m) & 7) * 16u);
        }
#pragma unroll
        for (int ct = 0; ct < 4; ct++) {
          int n = wv * 64 + ct * 16 + l15;
          bfr[s][ct] = *(const bf16x8*)(lds + bb + n * 128u + (((s * 4 + quad) + n) & 7) * 16u);
        }
      }
      if (p + 1 < 10) {
        stageB(w0b, 1280, LDS_B0 + ((p + 1) & 1) * 65536u, p + 1, 8);
        genF(p + 1, LDS_FB + ((p + 1) & 1) * 8192u);
      }
#pragma unroll
      for (int s = 0; s < 2; s++)
#pragma unroll
        for (int rt = 0; rt < 4; rt++)
#pragma unroll
          for (int ct = 0; ct < 4; ct++)
            acc[rt][ct] = __builtin_amdgcn_mfma_f32_16x16x32_bf16(af[s][rt], bfr[s][ct], acc[rt][ct], 0, 0, 0);
      __syncthreads();
    }
    // prefetch L1 tile 0 into B1 buf0 (B0/feat regions dead now)
    stageB(w1b, 1024, LDS_B1, 0, 6);
    // epilogue: bias+relu -> bf16 h0 at [0,65536), 64-chunk rotation
#pragma unroll
    for (int ct = 0; ct < 4; ct++) {
      int col = wv * 64 + ct * 16 + l15;
      float bias = b0[col];
      int kb = col >> 3, cr = (col & 7) * 2;
#pragma unroll
      for (int rt = 0; rt < 4; rt++)
#pragma unroll
        for (int vi = 0; vi < 4; vi++) {
          int rowm = rt * 16 + quad * 4 + vi;
          float v = fmaxf(acc[rt][ct][vi] + bias, 0.f);
          *(unsigned short*)(lds + rowm * 1024u + ((kb + rowm) & 63) * 16u + cr) = f2bf(v);
        }
    }
  }
  __syncthreads();

  // =================== Layer 1 : 512 -> 384 ===================
  {
    f32x4 acc[4][3];
#pragma unroll
    for (int a = 0; a < 4; a++)
#pragma unroll
      for (int c = 0; c < 3; c++) acc[a][c] = f32x4{0.f, 0.f, 0.f, 0.f};

    for (int p = 0; p < 8; p++) {
      unsigned bb = LDS_B1 + (p & 1) * 49152u;
      bf16x8 af[2][4], bfr[2][3];
#pragma unroll
      for (int s = 0; s < 2; s++) {
        int kc = p * 8 + s * 4 + quad;   // global 16B chunk of K
#pragma unroll
        for (int rt = 0; rt < 4; rt++) {
          int m = rt * 16 + l15;
          af[s][rt] = *(const bf16x8*)(lds + m * 1024u + ((kc + m) & 63) * 16u);
        }
#pragma unroll
        for (int ct = 0; ct < 3; ct++) {
          int n = wv * 48 + ct * 16 + l15;
          bfr[s][ct] = *(const bf16x8*)(lds + bb + n * 128u + (((s * 4 + quad) + n) & 7) * 16u);
        }
      }
      if (p + 1 < 8) stageB(w1b, 1024, LDS_B1 + ((p + 1) & 1) * 49152u, p + 1, 6);
#pragma unroll
      for (int s = 0; s < 2; s++)
#pragma unroll
        for (int rt = 0; rt < 4; rt++)
#pragma unroll
          for (int ct = 0; ct < 3; ct++)
            acc[rt][ct] = __builtin_amdgcn_mfma_f32_16x16x32_bf16(af[s][rt], bfr[s][ct], acc[rt][ct], 0, 0, 0);
      __syncthreads();
    }
    stageB(w2b, 768, LDS_B2, 0, 4);  // prefetch L2 tile 0
    // epilogue -> h1 at [0,49152) (h0 dead), 48-chunk rotation
#pragma unroll
    for (int ct = 0; ct < 3; ct++) {
      int col = wv * 48 + ct * 16 + l15;
      float bias = b1[col];
      int kb = col >> 3, cr = (col & 7) * 2;
#pragma unroll
      for (int rt = 0; rt < 4; rt++)
#pragma unroll
        for (int vi = 0; vi < 4; vi++) {
          int rowm = rt * 16 + quad * 4 + vi;
          int s = kb + rowm;
          if (s >= 48) s -= 48;
          if (s >= 48) s -= 48;
          float v = fmaxf(acc[rt][ct][vi] + bias, 0.f);
          *(unsigned short*)(lds + rowm * 768u + s * 16u + cr) = f2bf(v);
        }
    }
  }
  __syncthreads();

  // =================== Layer 2 : 384 -> 256, fused weighted reduction ==============
  {
    f32x4 acc[4][2];
#pragma unroll
    for (int a = 0; a < 4; a++)
#pragma unroll
      for (int c = 0; c < 2; c++) acc[a][c] = f32x4{0.f, 0.f, 0.f, 0.f};

    for (int p = 0; p < 6; p++) {
      unsigned bb = LDS_B2 + (p & 1) * 32768u;
      bf16x8 af[2][4], bfr[2][2];
#pragma unroll
      for (int s = 0; s < 2; s++) {
        int kc = p * 8 + s * 4 + quad;
#pragma unroll
        for (int rt = 0; rt < 4; rt++) {
          int m = rt * 16 + l15;
          int s48 = kc + m;
          if (s48 >= 48) s48 -= 48;
          if (s48 >= 48) s48 -= 48;
          af[s][rt] = *(const bf16x8*)(lds + m * 768u + s48 * 16u);
        }
#pragma unroll
        for (int ct = 0; ct < 2; ct++) {
          int n = wv * 32 + ct * 16 + l15;
          bfr[s][ct] = *(const bf16x8*)(lds + bb + n * 128u + (((s * 4 + quad) + n) & 7) * 16u);
        }
      }
      if (p + 1 < 6) stageB(w2b, 768, LDS_B2 + ((p + 1) & 1) * 32768u, p + 1, 4);
#pragma unroll
      for (int s = 0; s < 2; s++)
#pragma unroll
        for (int rt = 0; rt < 4; rt++)
#pragma unroll
          for (int ct = 0; ct < 2; ct++)
            acc[rt][ct] = __builtin_amdgcn_mfma_f32_16x16x32_bf16(af[s][rt], bfr[s][ct], acc[rt][ct], 0, 0, 0);
      __syncthreads();
    }

    // epilogue: relu(h2+b2) * softmax-wm, reduce over rows, atomicAdd into out
    int bi = r0 / 144;
    int boundary = (bi + 1) * 144;
#pragma unroll
    for (int ct = 0; ct < 2; ct++) {
      int col = wv * 32 + ct * 16 + l15;
      float bias = b2[col];
      const float* wmg = wm + (col >> 4) * 144;
      float s0 = 0.f, s1 = 0.f;
#pragma unroll
      for (int rt = 0; rt < 4; rt++)
#pragma unroll
        for (int vi = 0; vi < 4; vi++) {
          int r = r0 + rt * 16 + quad * 4 + vi;
          float v = fmaxf(acc[rt][ct][vi] + bias, 0.f);
          if (r < boundary) s0 += v * wmg[r - bi * 144];
          else              s1 += v * wmg[r - boundary];
        }
      s0 += __shfl_xor(s0, 16); s0 += __shfl_xor(s0, 32);
      s1 += __shfl_xor(s1, 16); s1 += __shfl_xor(s1, 32);
      if (quad == 0) {
        atomicAdd(out + bi * 256 + col, s0);
        if (boundary < r0 + 64) atomicAdd(out + (bi + 1) * 256 + col, s1);
      }
    }
  }
}

extern "C" void kernel_launch(void* const* d_in, const int* in_sizes, int n_in,
                              void* d_out, int out_size, void* d_ws, size_t ws_size,
                              hipStream_t stream) {
  (void)in_sizes; (void)n_in; (void)ws_size;
  const float* x     = (const float*)d_in[0];
  const float* w0    = (const float*)d_in[1];
  const float* b0    = (const float*)d_in[2];
  const float* w1    = (const float*)d_in[3];
  const float* b1    = (const float*)d_in[4];
  const float* w2    = (const float*)d_in[5];
  const float* b2    = (const float*)d_in[6];
  const float* wmask = (const float*)d_in[7];
  float* out = (float*)d_out;
  char* ws = (char*)d_ws;
  float* wm = (float*)ws;                                         // 16*144*4 = 9216
  unsigned short* w0b = (unsigned short*)(ws + 9216);             // 512*640*2 = 655360
  unsigned short* w1b = (unsigned short*)(ws + 9216 + 655360);    // 384*512*2 = 393216
  unsigned short* w2b = (unsigned short*)(ws + 9216 + 655360 + 393216);  // 256*384*2

  hipMemsetAsync(d_out, 0, (size_t)out_size * sizeof(float), stream);
  prep_conv<<<2432, 256, 0, stream>>>(w0, w1, w2, w0b, w1b, w2b);
  prep_wm<<<1, 1024, 0, stream>>>(wmask, wm);
  fused_main<<<2304, 512, 0, stream>>>(x, b0, b1, b2, w0b, w1b, w2b, wm, out);
}